// Round 6
// baseline (276.311 us; speedup 1.0000x reference)
//
#include <hip/hip_runtime.h>

// Problem constants (from reference)
constexpr int kB   = 128;
constexpr int kU   = 4;
constexpr int kNBS = 64;
constexpr int kS   = 408;
constexpr int kS4  = kS / 4;                               // 102 float4 per row
constexpr unsigned kThreads =
    (unsigned)kB * kU * (kNBS / 16) * kS4;                 // 208,896 (16 rows/thread)
constexpr float kEmW     = 0.01f;
constexpr float kInvNRad = 1.0f / ((float)kB * kU * kNBS * kS);
constexpr float kInvNAtt = 1.0f / ((float)kB * kU * kS);

// Native clang vector type — required by __builtin_nontemporal_load.
typedef float vfloat4 __attribute__((ext_vector_type(4)));

// R14: the R13 pipeline done RIGHT — named registers, no arrays.
//
// Session ledger:
//  R8/R12 (256,3), NT, chunk=8 one-shot: 44.2-44.9 us, VGPR=84  <- champion
//  R9  plain loads (no NT):              79.5 us — L2 thrash. Keep NT.
//  R11 (256,6):                         126.0 us — spill (WRITE=162MB).
//  R13 double-buffer via rr[2][4] arrays: 114.5 us — Rule #20: runtime-
//      indexed ext_vector arrays demoted to scratch (WRITE=120.8MB =
//      512 B/thread = exactly the 2x16x16B buffer; VGPR=84). The pipeline
//      theory was NOT tested — the implementation was broken.
//
// This version: 16 rows/thread = 4 tiles x 4 rows, double-buffered in 32
// NAMED vfloat4 registers (Arr0..Ati3 / Brr0..Bti3), straight-line
// macro-expanded issue/consume. 1 tile ahead in steady state -> 16-32 NT
// loads continuously in flight across the thread's life instead of one
// burst per thread. Grid 816 blocks = 1.06 generations at 3 blocks/CU
// (near-persistent); atten re-reads halve vs champion.
// Tripwires: WRITE_SIZE ~51 KB and VGPR_Count 140-170 expected.
//   VGPR~84 + MB-scale WRITE  -> scratch again -> revert to R12.
//   VGPR~84 + 51 KB WRITE     -> compiler serialized the pipeline; if
//                                dur ~44-47 us the service ceiling is real.
//
// Mapping: tid in [0, 208896).
//   s4  = tid % 102                    (fastest dim -> coalesced)
//   rem = tid / 102  in [0, 2048)
//   sub = rem % 4, bu = rem / 4        (bu in [0,512) = b*U+u)
//   rows r = bu*64 + sub*16 + t*4 + j, t=0..3, j=0..3; q = r*102 + s4
//   atten a = bu*102 + s4 — loaded once, reused for all 16 rows.

#define NTLOAD(p) __builtin_nontemporal_load(p)

// Issue one 4-row tile into buffer P (16 NT loads, row-interleaved so
// consumption order matches issue order -> incremental vmcnt waits).
#define ISSUE_TILE(P, T)                                                  \
  {                                                                       \
    const unsigned q0_ = qbase + (unsigned)(T) * (4u * 102u);             \
    P##rr0 = NTLOAD(&rad_re[q0_]);                                        \
    P##ri0 = NTLOAD(&rad_im[q0_]);                                        \
    P##tr0 = NTLOAD(&tgt_re[q0_]);                                        \
    P##ti0 = NTLOAD(&tgt_im[q0_]);                                        \
    P##rr1 = NTLOAD(&rad_re[q0_ + 102u]);                                 \
    P##ri1 = NTLOAD(&rad_im[q0_ + 102u]);                                 \
    P##tr1 = NTLOAD(&tgt_re[q0_ + 102u]);                                 \
    P##ti1 = NTLOAD(&tgt_im[q0_ + 102u]);                                 \
    P##rr2 = NTLOAD(&rad_re[q0_ + 204u]);                                 \
    P##ri2 = NTLOAD(&rad_im[q0_ + 204u]);                                 \
    P##tr2 = NTLOAD(&tgt_re[q0_ + 204u]);                                 \
    P##ti2 = NTLOAD(&tgt_im[q0_ + 204u]);                                 \
    P##rr3 = NTLOAD(&rad_re[q0_ + 306u]);                                 \
    P##ri3 = NTLOAD(&rad_im[q0_ + 306u]);                                 \
    P##tr3 = NTLOAD(&tgt_re[q0_ + 306u]);                                 \
    P##ti3 = NTLOAD(&tgt_im[q0_ + 306u]);                                 \
  }

// Consume one row (4 components). Math identical to champion.
#define ROW(RR, RI, TR, TI)                                               \
  {                                                                       \
    _Pragma("unroll")                                                     \
    for (int c = 0; c < 4; ++c) {                                         \
      const float r_r = (RR)[c], r_i = (RI)[c];                           \
      const float pr = ar[c] * r_r - ai[c] * r_i;                         \
      const float pi = ar[c] * r_i + ai[c] * r_r;                         \
      const float dr = pr - (TR)[c];                                      \
      const float di = pi - (TI)[c];                                      \
      recv = fmaf((dr * dr + di * di), w[c], recv);                       \
      float rm = sqrtf(fmaf(r_r, r_r, r_i * r_i)) - 10.0f;                \
      rm = fmaxf(rm, 0.0f);                                               \
      em_rad = fmaf(rm, rm, em_rad);                                      \
    }                                                                     \
  }

#define CONSUME_TILE(P)                                                   \
  ROW(P##rr0, P##ri0, P##tr0, P##ti0)                                     \
  ROW(P##rr1, P##ri1, P##tr1, P##ti1)                                     \
  ROW(P##rr2, P##ri2, P##tr2, P##ti2)                                     \
  ROW(P##rr3, P##ri3, P##tr3, P##ti3)

__global__ void __launch_bounds__(256, 3)
prism_loss_kernel(const vfloat4* __restrict__ atten_re,
                  const vfloat4* __restrict__ atten_im,
                  const vfloat4* __restrict__ rad_re,
                  const vfloat4* __restrict__ rad_im,
                  const vfloat4* __restrict__ tgt_re,
                  const vfloat4* __restrict__ tgt_im,
                  const vfloat4* __restrict__ weights,
                  float* __restrict__ out)
{
    const unsigned tid   = blockIdx.x * 256 + threadIdx.x;  // grid sized exactly
    const unsigned rem   = tid / 102u;                      // magic-mul div
    const unsigned s4    = tid - rem * 102u;
    const unsigned sub   = rem & 3u;
    const unsigned bu    = rem >> 2;
    const unsigned qbase = (bu * 64u + sub * 16u) * 102u + s4;
    const unsigned abase = bu * 102u + s4;
    const bool do_att = (sub == 0u);

    const vfloat4 w  = weights[s4];
    const vfloat4 ar = atten_re[abase];
    const vfloat4 ai = atten_im[abase];

    // Two named tile buffers: 32 vfloat4 = 128 VGPRs payload, all
    // compile-time register names (no arrays -> no scratch demotion).
    vfloat4 Arr0, Ari0, Atr0, Ati0, Arr1, Ari1, Atr1, Ati1;
    vfloat4 Arr2, Ari2, Atr2, Ati2, Arr3, Ari3, Atr3, Ati3;
    vfloat4 Brr0, Bri0, Btr0, Bti0, Brr1, Bri1, Btr1, Bti1;
    vfloat4 Brr2, Bri2, Btr2, Bti2, Brr3, Bri3, Btr3, Bti3;

    float recv   = 0.0f;
    float em_rad = 0.0f;
    float em_att = 0.0f;

    // Software pipeline: 1 tile ahead in steady state.
    ISSUE_TILE(A, 0)
    ISSUE_TILE(B, 1)
    CONSUME_TILE(A)
    ISSUE_TILE(A, 2)
    CONSUME_TILE(B)
    ISSUE_TILE(B, 3)
    CONSUME_TILE(A)
    CONSUME_TILE(B)

    if (do_att) {
        #pragma unroll
        for (int c = 0; c < 4; ++c) {
            float am = sqrtf(fmaf(ar[c], ar[c], ai[c] * ai[c])) - 1.0f;
            am = fmaxf(am, 0.0f);
            em_att = fmaf(am, am, em_att);
        }
    }

    float acc = recv + kEmW * (em_rad * kInvNRad + em_att * kInvNAtt);

    // Wave-64 reduction.
    #pragma unroll
    for (int off = 32; off > 0; off >>= 1)
        acc += __shfl_down(acc, off, 64);

    __shared__ float sdata[4];
    const int lane = threadIdx.x & 63;
    const int wave = threadIdx.x >> 6;
    if (lane == 0) sdata[wave] = acc;
    __syncthreads();
    if (threadIdx.x == 0) {
        atomicAdd(out, sdata[0] + sdata[1] + sdata[2] + sdata[3]);
    }
}

extern "C" void kernel_launch(void* const* d_in, const int* in_sizes, int n_in,
                              void* d_out, int out_size, void* d_ws, size_t ws_size,
                              hipStream_t stream) {
    const vfloat4* atten_re = (const vfloat4*)d_in[0];
    const vfloat4* atten_im = (const vfloat4*)d_in[1];
    const vfloat4* rad_re   = (const vfloat4*)d_in[2];
    const vfloat4* rad_im   = (const vfloat4*)d_in[3];
    const vfloat4* tgt_re   = (const vfloat4*)d_in[4];
    const vfloat4* tgt_im   = (const vfloat4*)d_in[5];
    const vfloat4* weights  = (const vfloat4*)d_in[6];
    float* out = (float*)d_out;

    // d_out is re-poisoned to 0xAA before every timed launch; zero it.
    (void)hipMemsetAsync(out, 0, sizeof(float), stream);

    // 816 blocks * 256 threads == kThreads exactly (no bounds checks needed).
    prism_loss_kernel<<<(int)(kThreads / 256), 256, 0, stream>>>(
        atten_re, atten_im, rad_re, rad_im, tgt_re, tgt_im, weights, out);
}